// Round 1
// baseline (1040.751 us; speedup 1.0000x reference)
//
#include <hip/hip_runtime.h>
#include <hip/hip_bf16.h>

#define N_NODES 40000
#define N_EDGES 640000
#define DIM 128
#define N_OPS 5
#define EPS 1e-5f

// ---- monotonic uint encoding of float: a<b  <=>  enc(a)<enc(b) (unsigned) ----
// enc identity element is 0u (below enc of every real float, incl. -inf).
__device__ __forceinline__ unsigned enc_f32(float x) {
  unsigned b = __float_as_uint(x);
  return (b & 0x80000000u) ? ~b : (b | 0x80000000u);
}
__device__ __forceinline__ float dec_f32(unsigned e) {
  unsigned b = (e & 0x80000000u) ? (e ^ 0x80000000u) : ~e;
  return __uint_as_float(b);
}

// ---- K1: per-edge scatter.  wave (64 lanes) per edge, 2 dims per lane ----
__global__ void scatter_kernel(const int* __restrict__ ei,
                               const float* __restrict__ h,
                               float* __restrict__ agg_sum,
                               unsigned* __restrict__ agg_max,
                               float* __restrict__ deg) {
  const int lane  = threadIdx.x & 63;
  const int wave  = (int)((blockIdx.x * blockDim.x + threadIdx.x) >> 6);
  const int nwave = (int)((gridDim.x * blockDim.x) >> 6);
  for (int e = wave; e < N_EDGES; e += nwave) {
    const int src = ei[e];
    const int dst = ei[N_EDGES + e];
    const float2 v = *reinterpret_cast<const float2*>(h + (size_t)src * DIM + lane * 2);
    float*    sp = agg_sum + (size_t)dst * DIM + lane * 2;
    unsigned* mp = agg_max + (size_t)dst * DIM + lane * 2;
    unsafeAtomicAdd(sp,     v.x);
    unsafeAtomicAdd(sp + 1, v.y);
    atomicMax(mp,     enc_f32(v.x));
    atomicMax(mp + 1, enc_f32(v.y));
    if (lane == 0) unsafeAtomicAdd(deg + dst, 1.0f);
  }
}

// ---- K2: per-branch column sums / sumsq over nodes ----
__global__ void stats_kernel(const float* __restrict__ h,
                             const float* __restrict__ h_in,
                             const float* __restrict__ agg_sum,
                             const unsigned* __restrict__ agg_max,
                             const float* __restrict__ deg,
                             float* __restrict__ ssum,
                             float* __restrict__ sssq) {
  const int d = threadIdx.x;  // 128 threads: one column each
  float s0 = 0, s1 = 0, s2 = 0, s3 = 0, s4 = 0;
  float q0 = 0, q1 = 0, q2 = 0, q3 = 0, q4 = 0;
  for (int n = blockIdx.x; n < N_NODES; n += gridDim.x) {
    const size_t off = (size_t)n * DIM + d;
    const float dg  = deg[n];
    const float inv = 1.0f / fmaxf(dg, 1.0f);
    const float v0 = h[off];
    const float v1 = h_in[off];
    const float v2 = agg_sum[off];
    const float v3 = v2 * inv;
    const float v4 = (dg > 0.0f) ? dec_f32(agg_max[off]) : 0.0f;
    s0 += v0; q0 += v0 * v0;
    s1 += v1; q1 += v1 * v1;
    s2 += v2; q2 += v2 * v2;
    s3 += v3; q3 += v3 * v3;
    s4 += v4; q4 += v4 * v4;
  }
  unsafeAtomicAdd(&ssum[0 * DIM + d], s0); unsafeAtomicAdd(&sssq[0 * DIM + d], q0);
  unsafeAtomicAdd(&ssum[1 * DIM + d], s1); unsafeAtomicAdd(&sssq[1 * DIM + d], q1);
  unsafeAtomicAdd(&ssum[2 * DIM + d], s2); unsafeAtomicAdd(&sssq[2 * DIM + d], q2);
  unsafeAtomicAdd(&ssum[3 * DIM + d], s3); unsafeAtomicAdd(&sssq[3 * DIM + d], q3);
  unsafeAtomicAdd(&ssum[4 * DIM + d], s4); unsafeAtomicAdd(&sssq[4 * DIM + d], q4);
}

// ---- K3: mu / rsig ----
__global__ void finalize_stats(const float* __restrict__ ssum,
                               const float* __restrict__ sssq,
                               float* __restrict__ mu,
                               float* __restrict__ rsig) {
  const int i = blockIdx.x * blockDim.x + threadIdx.x;
  if (i < N_OPS * DIM) {
    const float invn = 1.0f / (float)N_NODES;
    const float m = ssum[i] * invn;
    float v = sssq[i] * invn - m * m;
    v = fmaxf(v, 0.0f);
    mu[i]   = m;
    rsig[i] = rsqrtf(v + EPS);
  }
}

// ---- K4: fused BN + ReLU + weighted sum, float4 ----
__global__ void out_kernel(const float* __restrict__ h,
                           const float* __restrict__ h_in,
                           const float* __restrict__ agg_sum,
                           const unsigned* __restrict__ agg_max,
                           const float* __restrict__ deg,
                           const float* __restrict__ mu,
                           const float* __restrict__ rsig,
                           const float* __restrict__ gamma,
                           const float* __restrict__ beta,
                           const float* __restrict__ w,
                           float* __restrict__ out) {
  __shared__ float smu[N_OPS * DIM], srs[N_OPS * DIM], sg[N_OPS * DIM], sb[N_OPS * DIM];
  __shared__ float sw[N_OPS];
  for (int i = threadIdx.x; i < N_OPS * DIM; i += blockDim.x) {
    smu[i] = mu[i]; srs[i] = rsig[i]; sg[i] = gamma[i]; sb[i] = beta[i];
  }
  if (threadIdx.x < N_OPS) sw[threadIdx.x] = w[threadIdx.x];
  __syncthreads();

  const int ngroups = N_NODES * (DIM / 4);
  for (int g = blockIdx.x * blockDim.x + threadIdx.x; g < ngroups;
       g += gridDim.x * blockDim.x) {
    const int n  = g >> 5;          // 32 float4 groups per node
    const int d4 = (g & 31) * 4;
    const size_t off = (size_t)n * DIM + d4;

    const float4 v0 = *reinterpret_cast<const float4*>(h + off);
    const float4 v1 = *reinterpret_cast<const float4*>(h_in + off);
    const float4 v2 = *reinterpret_cast<const float4*>(agg_sum + off);
    const uint4  e4 = *reinterpret_cast<const uint4*>(agg_max + off);
    const float dg  = deg[n];
    const float inv = 1.0f / fmaxf(dg, 1.0f);

    float vals[N_OPS][4];
    vals[0][0] = v0.x; vals[0][1] = v0.y; vals[0][2] = v0.z; vals[0][3] = v0.w;
    vals[1][0] = v1.x; vals[1][1] = v1.y; vals[1][2] = v1.z; vals[1][3] = v1.w;
    vals[2][0] = v2.x; vals[2][1] = v2.y; vals[2][2] = v2.z; vals[2][3] = v2.w;
    vals[3][0] = v2.x * inv; vals[3][1] = v2.y * inv;
    vals[3][2] = v2.z * inv; vals[3][3] = v2.w * inv;
    if (dg > 0.0f) {
      vals[4][0] = dec_f32(e4.x); vals[4][1] = dec_f32(e4.y);
      vals[4][2] = dec_f32(e4.z); vals[4][3] = dec_f32(e4.w);
    } else {
      vals[4][0] = 0.0f; vals[4][1] = 0.0f; vals[4][2] = 0.0f; vals[4][3] = 0.0f;
    }

    float acc[4] = {0.0f, 0.0f, 0.0f, 0.0f};
#pragma unroll
    for (int b = 0; b < N_OPS; ++b) {
      const float wb = sw[b];
#pragma unroll
      for (int c = 0; c < 4; ++c) {
        const int dd = b * DIM + d4 + c;
        const float xh = (vals[b][c] - smu[dd]) * srs[dd];
        const float y  = fmaf(sg[dd], xh, sb[dd]);
        acc[c] = fmaf(wb, fmaxf(y, 0.0f), acc[c]);
      }
    }
    *reinterpret_cast<float4*>(out + off) = make_float4(acc[0], acc[1], acc[2], acc[3]);
  }
}

extern "C" void kernel_launch(void* const* d_in, const int* in_sizes, int n_in,
                              void* d_out, int out_size, void* d_ws, size_t ws_size,
                              hipStream_t stream) {
  const float* w     = (const float*)d_in[0];
  const int*   ei    = (const int*)d_in[1];
  const float* h     = (const float*)d_in[2];
  const float* h_in  = (const float*)d_in[3];
  const float* gamma = (const float*)d_in[4];
  const float* beta  = (const float*)d_in[5];
  float* out = (float*)d_out;

  const size_t ND = (size_t)N_NODES * DIM;
  float*    ws      = (float*)d_ws;
  float*    agg_sum = ws;                       // ND floats
  unsigned* agg_max = (unsigned*)(ws + ND);     // ND uints (monotone-encoded)
  float*    deg     = ws + 2 * ND;              // N_NODES floats
  float*    ssum    = deg + N_NODES;            // 640
  float*    sssq    = ssum + N_OPS * DIM;       // 640
  float*    mu      = sssq + N_OPS * DIM;       // 640
  float*    rsig    = mu + N_OPS * DIM;         // 640

  const size_t zero_bytes = (2 * ND + N_NODES + 2 * (size_t)N_OPS * DIM) * sizeof(float);
  hipMemsetAsync(d_ws, 0, zero_bytes, stream);  // 0 == identity for sum, deg, stats, enc-max

  scatter_kernel<<<2048, 256, 0, stream>>>(ei, h, agg_sum, agg_max, deg);
  stats_kernel<<<1024, 128, 0, stream>>>(h, h_in, agg_sum, agg_max, deg, ssum, sssq);
  finalize_stats<<<(N_OPS * DIM + 255) / 256, 256, 0, stream>>>(ssum, sssq, mu, rsig);
  out_kernel<<<2048, 256, 0, stream>>>(h, h_in, agg_sum, agg_max, deg, mu, rsig,
                                       gamma, beta, w, out);
}

// Round 2
// 207.873 us; speedup vs baseline: 5.0067x; 5.0067x over previous
//
#include <hip/hip_runtime.h>
#include <hip/hip_bf16.h>

#define N_NODES 40000
#define N_EDGES 640000
#define DIM 128
#define N_OPS 5
#define EPS 1e-5f

// ---- K1: histogram of dst ----
__global__ void hist_kernel(const int* __restrict__ ei, int* __restrict__ cnt) {
  const int e = blockIdx.x * blockDim.x + threadIdx.x;
  if (e < N_EDGES) atomicAdd(&cnt[ei[N_EDGES + e]], 1);
}

// ---- K2: single-block exclusive scan over 40k counts (shfl + LDS) ----
__global__ void scan_kernel(const int* __restrict__ cnt, int* __restrict__ offs,
                            int* __restrict__ cursor) {
  __shared__ int wsum[16];
  const int tid  = threadIdx.x;       // 1024 threads
  const int lane = tid & 63;
  const int wid  = tid >> 6;
  int carry = 0;
  for (int base = 0; base < N_NODES; base += 1024) {
    const int i = base + tid;
    const int x = (i < N_NODES) ? cnt[i] : 0;
    int v = x;  // inclusive wave scan
#pragma unroll
    for (int off = 1; off < 64; off <<= 1) {
      int t = __shfl_up(v, off, 64);
      if (lane >= off) v += t;
    }
    if (lane == 63) wsum[wid] = v;
    __syncthreads();
    if (wid == 0 && lane < 16) {
      int wv = wsum[lane];
#pragma unroll
      for (int off = 1; off < 16; off <<= 1) {
        int t = __shfl_up(wv, off, 64);
        if (lane >= off) wv += t;
      }
      wsum[lane] = wv;  // inclusive scan of wave sums
    }
    __syncthreads();
    const int wave_excl = (wid == 0) ? 0 : wsum[wid - 1];
    const int excl = v - x + wave_excl + carry;
    if (i < N_NODES) { offs[i] = excl; cursor[i] = excl; }
    carry += wsum[15];
    __syncthreads();  // protect wsum before next chunk
  }
  if (tid == 0) offs[N_NODES] = carry;
}

// ---- K3: fill CSR (src ids grouped by dst) ----
__global__ void csr_fill_kernel(const int* __restrict__ ei, int* __restrict__ cursor,
                                int* __restrict__ csr_src) {
  const int e = blockIdx.x * blockDim.x + threadIdx.x;
  if (e < N_EDGES) {
    const int pos = atomicAdd(&cursor[ei[N_EDGES + e]], 1);
    csr_src[pos] = ei[e];
  }
}

// ---- K4: wave-per-node gather segment-reduce (sum + max), no atomics ----
__global__ void gather_kernel(const int* __restrict__ csr_src,
                              const int* __restrict__ offs,
                              const float* __restrict__ h,
                              float* __restrict__ agg_sum,
                              float* __restrict__ agg_max,
                              float* __restrict__ deg) {
  const int lane  = threadIdx.x & 63;
  const int wave  = (int)((blockIdx.x * blockDim.x + threadIdx.x) >> 6);
  const int nwave = (int)((gridDim.x * blockDim.x) >> 6);
  for (int n = wave; n < N_NODES; n += nwave) {
    const int beg = offs[n], end = offs[n + 1];
    float sx = 0.f, sy = 0.f;
    float mx = -INFINITY, my = -INFINITY;
    int e = beg;
    for (; e + 3 < end; e += 4) {
      const int s0 = csr_src[e], s1 = csr_src[e + 1];
      const int s2 = csr_src[e + 2], s3 = csr_src[e + 3];
      const float2 a = *reinterpret_cast<const float2*>(h + (size_t)s0 * DIM + lane * 2);
      const float2 b = *reinterpret_cast<const float2*>(h + (size_t)s1 * DIM + lane * 2);
      const float2 c = *reinterpret_cast<const float2*>(h + (size_t)s2 * DIM + lane * 2);
      const float2 d = *reinterpret_cast<const float2*>(h + (size_t)s3 * DIM + lane * 2);
      sx += a.x + b.x + c.x + d.x;
      sy += a.y + b.y + c.y + d.y;
      mx = fmaxf(fmaxf(fmaxf(mx, a.x), fmaxf(b.x, c.x)), d.x);
      my = fmaxf(fmaxf(fmaxf(my, a.y), fmaxf(b.y, c.y)), d.y);
    }
    for (; e < end; ++e) {
      const int s0 = csr_src[e];
      const float2 a = *reinterpret_cast<const float2*>(h + (size_t)s0 * DIM + lane * 2);
      sx += a.x; sy += a.y;
      mx = fmaxf(mx, a.x); my = fmaxf(my, a.y);
    }
    const int dg = end - beg;
    if (dg == 0) { mx = 0.f; my = 0.f; }  // empty segment -> 0 (isfinite mask)
    *reinterpret_cast<float2*>(agg_sum + (size_t)n * DIM + lane * 2) = make_float2(sx, sy);
    *reinterpret_cast<float2*>(agg_max + (size_t)n * DIM + lane * 2) = make_float2(mx, my);
    if (lane == 0) deg[n] = (float)dg;
  }
}

// ---- K5: per-branch column sums / sumsq over nodes ----
__global__ void stats_kernel(const float* __restrict__ h,
                             const float* __restrict__ h_in,
                             const float* __restrict__ agg_sum,
                             const float* __restrict__ agg_max,
                             const float* __restrict__ deg,
                             float* __restrict__ ssum,
                             float* __restrict__ sssq) {
  const int d = threadIdx.x;  // 128 threads: one column each
  float s0 = 0, s1 = 0, s2 = 0, s3 = 0, s4 = 0;
  float q0 = 0, q1 = 0, q2 = 0, q3 = 0, q4 = 0;
  for (int n = blockIdx.x; n < N_NODES; n += gridDim.x) {
    const size_t off = (size_t)n * DIM + d;
    const float dg  = deg[n];
    const float inv = 1.0f / fmaxf(dg, 1.0f);
    const float v0 = h[off];
    const float v1 = h_in[off];
    const float v2 = agg_sum[off];
    const float v3 = v2 * inv;
    const float v4 = agg_max[off];
    s0 += v0; q0 += v0 * v0;
    s1 += v1; q1 += v1 * v1;
    s2 += v2; q2 += v2 * v2;
    s3 += v3; q3 += v3 * v3;
    s4 += v4; q4 += v4 * v4;
  }
  unsafeAtomicAdd(&ssum[0 * DIM + d], s0); unsafeAtomicAdd(&sssq[0 * DIM + d], q0);
  unsafeAtomicAdd(&ssum[1 * DIM + d], s1); unsafeAtomicAdd(&sssq[1 * DIM + d], q1);
  unsafeAtomicAdd(&ssum[2 * DIM + d], s2); unsafeAtomicAdd(&sssq[2 * DIM + d], q2);
  unsafeAtomicAdd(&ssum[3 * DIM + d], s3); unsafeAtomicAdd(&sssq[3 * DIM + d], q3);
  unsafeAtomicAdd(&ssum[4 * DIM + d], s4); unsafeAtomicAdd(&sssq[4 * DIM + d], q4);
}

// ---- K6: mu / rsig ----
__global__ void finalize_stats(const float* __restrict__ ssum,
                               const float* __restrict__ sssq,
                               float* __restrict__ mu,
                               float* __restrict__ rsig) {
  const int i = blockIdx.x * blockDim.x + threadIdx.x;
  if (i < N_OPS * DIM) {
    const float invn = 1.0f / (float)N_NODES;
    const float m = ssum[i] * invn;
    float v = sssq[i] * invn - m * m;
    v = fmaxf(v, 0.0f);
    mu[i]   = m;
    rsig[i] = rsqrtf(v + EPS);
  }
}

// ---- K7: fused BN + ReLU + weighted sum, float4 (reads agg_max in-place from d_out) ----
__global__ void out_kernel(const float* __restrict__ h,
                           const float* __restrict__ h_in,
                           const float* __restrict__ agg_sum,
                           const float* __restrict__ agg_max,
                           const float* __restrict__ deg,
                           const float* __restrict__ mu,
                           const float* __restrict__ rsig,
                           const float* __restrict__ gamma,
                           const float* __restrict__ beta,
                           const float* __restrict__ w,
                           float* __restrict__ out) {
  __shared__ float smu[N_OPS * DIM], srs[N_OPS * DIM], sg[N_OPS * DIM], sb[N_OPS * DIM];
  __shared__ float sw[N_OPS];
  for (int i = threadIdx.x; i < N_OPS * DIM; i += blockDim.x) {
    smu[i] = mu[i]; srs[i] = rsig[i]; sg[i] = gamma[i]; sb[i] = beta[i];
  }
  if (threadIdx.x < N_OPS) sw[threadIdx.x] = w[threadIdx.x];
  __syncthreads();

  const int ngroups = N_NODES * (DIM / 4);
  for (int g = blockIdx.x * blockDim.x + threadIdx.x; g < ngroups;
       g += gridDim.x * blockDim.x) {
    const int n  = g >> 5;          // 32 float4 groups per node
    const int d4 = (g & 31) * 4;
    const size_t off = (size_t)n * DIM + d4;

    const float4 v0 = *reinterpret_cast<const float4*>(h + off);
    const float4 v1 = *reinterpret_cast<const float4*>(h_in + off);
    const float4 v2 = *reinterpret_cast<const float4*>(agg_sum + off);
    const float4 v4 = *reinterpret_cast<const float4*>(agg_max + off);
    const float dg  = deg[n];
    const float inv = 1.0f / fmaxf(dg, 1.0f);

    float vals[N_OPS][4];
    vals[0][0] = v0.x; vals[0][1] = v0.y; vals[0][2] = v0.z; vals[0][3] = v0.w;
    vals[1][0] = v1.x; vals[1][1] = v1.y; vals[1][2] = v1.z; vals[1][3] = v1.w;
    vals[2][0] = v2.x; vals[2][1] = v2.y; vals[2][2] = v2.z; vals[2][3] = v2.w;
    vals[3][0] = v2.x * inv; vals[3][1] = v2.y * inv;
    vals[3][2] = v2.z * inv; vals[3][3] = v2.w * inv;
    vals[4][0] = v4.x; vals[4][1] = v4.y; vals[4][2] = v4.z; vals[4][3] = v4.w;

    float acc[4] = {0.0f, 0.0f, 0.0f, 0.0f};
#pragma unroll
    for (int b = 0; b < N_OPS; ++b) {
      const float wb = sw[b];
#pragma unroll
      for (int c = 0; c < 4; ++c) {
        const int dd = b * DIM + d4 + c;
        const float xh = (vals[b][c] - smu[dd]) * srs[dd];
        const float y  = fmaf(sg[dd], xh, sb[dd]);
        acc[c] = fmaf(wb, fmaxf(y, 0.0f), acc[c]);
      }
    }
    *reinterpret_cast<float4*>(out + off) = make_float4(acc[0], acc[1], acc[2], acc[3]);
  }
}

extern "C" void kernel_launch(void* const* d_in, const int* in_sizes, int n_in,
                              void* d_out, int out_size, void* d_ws, size_t ws_size,
                              hipStream_t stream) {
  const float* w     = (const float*)d_in[0];
  const int*   ei    = (const int*)d_in[1];
  const float* h     = (const float*)d_in[2];
  const float* h_in  = (const float*)d_in[3];
  const float* gamma = (const float*)d_in[4];
  const float* beta  = (const float*)d_in[5];
  float* out = (float*)d_out;

  const size_t ND = (size_t)N_NODES * DIM;
  // Workspace layout (agg_max lives in d_out to bound ws usage):
  float* ws       = (float*)d_ws;
  float* agg_sum  = ws;                               // ND floats   (16B aligned)
  int*   cnt      = (int*)(ws + ND);                  // N ints      <- zeroed
  float* ssum     = (float*)(cnt + N_NODES);          // 640         <- zeroed
  float* sssq     = ssum + N_OPS * DIM;               // 640         <- zeroed
  float* mu       = sssq + N_OPS * DIM;               // 640
  float* rsig     = mu + N_OPS * DIM;                 // 640
  int*   offs     = (int*)(rsig + N_OPS * DIM);       // N+1 ints
  int*   cursor   = offs + N_NODES + 1;               // N ints
  float* deg      = (float*)(cursor + N_NODES);       // N floats
  int*   csr_src  = (int*)(deg + N_NODES);            // E ints
  float* agg_max  = out;                              // ND floats (overwritten by out_kernel last)

  // zero: cnt + ssum + sssq (contiguous)
  hipMemsetAsync(cnt, 0, (N_NODES + 2 * N_OPS * DIM) * sizeof(int), stream);

  hist_kernel<<<(N_EDGES + 255) / 256, 256, 0, stream>>>(ei, cnt);
  scan_kernel<<<1, 1024, 0, stream>>>(cnt, offs, cursor);
  csr_fill_kernel<<<(N_EDGES + 255) / 256, 256, 0, stream>>>(ei, cursor, csr_src);
  gather_kernel<<<2048, 256, 0, stream>>>(csr_src, offs, h, agg_sum, agg_max, deg);
  stats_kernel<<<1024, 128, 0, stream>>>(h, h_in, agg_sum, agg_max, deg, ssum, sssq);
  finalize_stats<<<(N_OPS * DIM + 255) / 256, 256, 0, stream>>>(ssum, sssq, mu, rsig);
  out_kernel<<<2048, 256, 0, stream>>>(h, h_in, agg_sum, agg_max, deg, mu, rsig,
                                       gamma, beta, w, out);
}

// Round 3
// 202.450 us; speedup vs baseline: 5.1408x; 1.0268x over previous
//
#include <hip/hip_runtime.h>
#include <hip/hip_bf16.h>

#define N_NODES 40000
#define N_EDGES 640000
#define DIM 128
#define N_OPS 5
#define EPS 1e-5f

// ---- K1: histogram of dst ----
__global__ void hist_kernel(const int* __restrict__ ei, int* __restrict__ cnt) {
  const int e = blockIdx.x * blockDim.x + threadIdx.x;
  if (e < N_EDGES) atomicAdd(&cnt[ei[N_EDGES + e]], 1);
}

// ---- K2: single-block exclusive scan over 40k counts (int4/thread) ----
__global__ void scan_kernel(const int* __restrict__ cnt, int* __restrict__ offs,
                            int* __restrict__ cursor) {
  __shared__ int wsum[16];
  const int tid  = threadIdx.x;       // 1024 threads
  const int lane = tid & 63;
  const int wid  = tid >> 6;
  int carry = 0;
  for (int base = 0; base < N_NODES; base += 4096) {
    const int i0 = base + tid * 4;
    int x0 = 0, x1 = 0, x2 = 0, x3 = 0;
    if (i0 + 3 < N_NODES) {
      const int4 x4 = *reinterpret_cast<const int4*>(cnt + i0);
      x0 = x4.x; x1 = x4.y; x2 = x4.z; x3 = x4.w;
    } else if (i0 < N_NODES) {
      x0 = cnt[i0];
      if (i0 + 1 < N_NODES) x1 = cnt[i0 + 1];
      if (i0 + 2 < N_NODES) x2 = cnt[i0 + 2];
    }
    const int my4 = x0 + x1 + x2 + x3;
    int v = my4;  // inclusive wave scan of per-thread sums
#pragma unroll
    for (int off = 1; off < 64; off <<= 1) {
      int t = __shfl_up(v, off, 64);
      if (lane >= off) v += t;
    }
    if (lane == 63) wsum[wid] = v;
    __syncthreads();
    if (wid == 0 && lane < 16) {
      int wv = wsum[lane];
#pragma unroll
      for (int off = 1; off < 16; off <<= 1) {
        int t = __shfl_up(wv, off, 64);
        if (lane >= off) wv += t;
      }
      wsum[lane] = wv;
    }
    __syncthreads();
    const int wave_excl = (wid == 0) ? 0 : wsum[wid - 1];
    int excl = v - my4 + wave_excl + carry;
    if (i0 < N_NODES) {
      offs[i0] = excl; cursor[i0] = excl; excl += x0;
      if (i0 + 1 < N_NODES) { offs[i0 + 1] = excl; cursor[i0 + 1] = excl; excl += x1; }
      if (i0 + 2 < N_NODES) { offs[i0 + 2] = excl; cursor[i0 + 2] = excl; excl += x2; }
      if (i0 + 3 < N_NODES) { offs[i0 + 3] = excl; cursor[i0 + 3] = excl; }
    }
    carry += wsum[15];
    __syncthreads();
  }
  if (tid == 0) offs[N_NODES] = carry;
}

// ---- K3: fill CSR (src ids grouped by dst) ----
__global__ void csr_fill_kernel(const int* __restrict__ ei, int* __restrict__ cursor,
                                int* __restrict__ csr_src) {
  const int e = blockIdx.x * blockDim.x + threadIdx.x;
  if (e < N_EDGES) {
    const int pos = atomicAdd(&cursor[ei[N_EDGES + e]], 1);
    csr_src[pos] = ei[e];
  }
}

// ---- K4: column sums/sumsq for branches 0,1 (h, h_in) — BW-bound float4 ----
__global__ void stats_h_kernel(const float* __restrict__ h,
                               const float* __restrict__ h_in,
                               float* __restrict__ ssum,
                               float* __restrict__ sssq) {
  __shared__ float lsum[2 * DIM], lssq[2 * DIM];
  for (int i = threadIdx.x; i < 2 * DIM; i += blockDim.x) { lsum[i] = 0.f; lssq[i] = 0.f; }
  __syncthreads();

  const int NG = N_NODES * (DIM / 4);
  const int stride = gridDim.x * blockDim.x;            // 512*256 = 131072, mult of 32
  float s0[4] = {0, 0, 0, 0}, q0[4] = {0, 0, 0, 0};
  float s1[4] = {0, 0, 0, 0}, q1[4] = {0, 0, 0, 0};
  for (int g = blockIdx.x * blockDim.x + threadIdx.x; g < NG; g += stride) {
    const float4 a = reinterpret_cast<const float4*>(h)[g];
    const float4 b = reinterpret_cast<const float4*>(h_in)[g];
    s0[0] += a.x; q0[0] += a.x * a.x;  s0[1] += a.y; q0[1] += a.y * a.y;
    s0[2] += a.z; q0[2] += a.z * a.z;  s0[3] += a.w; q0[3] += a.w * a.w;
    s1[0] += b.x; q1[0] += b.x * b.x;  s1[1] += b.y; q1[1] += b.y * b.y;
    s1[2] += b.z; q1[2] += b.z * b.z;  s1[3] += b.w; q1[3] += b.w * b.w;
  }
  const int c4 = (threadIdx.x & 31) * 4;  // stride ≡ 0 mod 32 → col group constant
#pragma unroll
  for (int j = 0; j < 4; ++j) {
    atomicAdd(&lsum[0 * DIM + c4 + j], s0[j]); atomicAdd(&lssq[0 * DIM + c4 + j], q0[j]);
    atomicAdd(&lsum[1 * DIM + c4 + j], s1[j]); atomicAdd(&lssq[1 * DIM + c4 + j], q1[j]);
  }
  __syncthreads();
  for (int i = threadIdx.x; i < 2 * DIM; i += blockDim.x) {
    unsafeAtomicAdd(&ssum[i], lsum[i]);
    unsafeAtomicAdd(&sssq[i], lssq[i]);
  }
}

// ---- K5: wave-per-node gather segment-reduce (sum + max) + fused stats b2,b3,b4 ----
__global__ void gather_kernel(const int* __restrict__ csr_src,
                              const int* __restrict__ offs,
                              const float* __restrict__ h,
                              float* __restrict__ agg_sum,
                              float* __restrict__ agg_max,
                              float* __restrict__ deg,
                              float* __restrict__ ssum,
                              float* __restrict__ sssq) {
  __shared__ float lsum[3 * DIM], lssq[3 * DIM];
  for (int i = threadIdx.x; i < 3 * DIM; i += blockDim.x) { lsum[i] = 0.f; lssq[i] = 0.f; }
  __syncthreads();

  const int lane  = threadIdx.x & 63;
  const int wave  = (int)((blockIdx.x * blockDim.x + threadIdx.x) >> 6);
  const int nwave = (int)((gridDim.x * blockDim.x) >> 6);
  // per-lane column-stat accumulators for cols 2*lane ("A") and 2*lane+1 ("B")
  float sA2 = 0, qA2 = 0, sA3 = 0, qA3 = 0, sA4 = 0, qA4 = 0;
  float sB2 = 0, qB2 = 0, sB3 = 0, qB3 = 0, sB4 = 0, qB4 = 0;

  for (int n = wave; n < N_NODES; n += nwave) {
    const int beg = offs[n], end = offs[n + 1];
    float sx = 0.f, sy = 0.f;
    float mx = -INFINITY, my = -INFINITY;
    int e = beg;
    for (; e + 7 < end; e += 8) {
      float2 r[8];
#pragma unroll
      for (int k = 0; k < 8; ++k) {
        const int s = csr_src[e + k];
        r[k] = *reinterpret_cast<const float2*>(h + (size_t)s * DIM + lane * 2);
      }
#pragma unroll
      for (int k = 0; k < 8; ++k) {
        sx += r[k].x; sy += r[k].y;
        mx = fmaxf(mx, r[k].x); my = fmaxf(my, r[k].y);
      }
    }
    for (; e < end; ++e) {
      const int s = csr_src[e];
      const float2 a = *reinterpret_cast<const float2*>(h + (size_t)s * DIM + lane * 2);
      sx += a.x; sy += a.y;
      mx = fmaxf(mx, a.x); my = fmaxf(my, a.y);
    }
    const int dg = end - beg;
    if (dg == 0) { mx = 0.f; my = 0.f; }  // empty segment -> 0 (isfinite mask)
    *reinterpret_cast<float2*>(agg_sum + (size_t)n * DIM + lane * 2) = make_float2(sx, sy);
    *reinterpret_cast<float2*>(agg_max + (size_t)n * DIM + lane * 2) = make_float2(mx, my);
    if (lane == 0) deg[n] = (float)dg;

    const float inv = 1.0f / fmaxf((float)dg, 1.0f);
    const float mnx = sx * inv, mny = sy * inv;
    sA2 += sx;  qA2 += sx * sx;   sB2 += sy;  qB2 += sy * sy;
    sA3 += mnx; qA3 += mnx * mnx; sB3 += mny; qB3 += mny * mny;
    sA4 += mx;  qA4 += mx * mx;   sB4 += my;  qB4 += my * my;
  }

  const int cA = 2 * lane, cB = 2 * lane + 1;
  atomicAdd(&lsum[0 * DIM + cA], sA2); atomicAdd(&lssq[0 * DIM + cA], qA2);
  atomicAdd(&lsum[0 * DIM + cB], sB2); atomicAdd(&lssq[0 * DIM + cB], qB2);
  atomicAdd(&lsum[1 * DIM + cA], sA3); atomicAdd(&lssq[1 * DIM + cA], qA3);
  atomicAdd(&lsum[1 * DIM + cB], sB3); atomicAdd(&lssq[1 * DIM + cB], qB3);
  atomicAdd(&lsum[2 * DIM + cA], sA4); atomicAdd(&lssq[2 * DIM + cA], qA4);
  atomicAdd(&lsum[2 * DIM + cB], sB4); atomicAdd(&lssq[2 * DIM + cB], qB4);
  __syncthreads();
  for (int i = threadIdx.x; i < 3 * DIM; i += blockDim.x) {
    unsafeAtomicAdd(&ssum[2 * DIM + i], lsum[i]);
    unsafeAtomicAdd(&sssq[2 * DIM + i], lssq[i]);
  }
}

// ---- K6: mu / rsig ----
__global__ void finalize_stats(const float* __restrict__ ssum,
                               const float* __restrict__ sssq,
                               float* __restrict__ mu,
                               float* __restrict__ rsig) {
  const int i = blockIdx.x * blockDim.x + threadIdx.x;
  if (i < N_OPS * DIM) {
    const float invn = 1.0f / (float)N_NODES;
    const float m = ssum[i] * invn;
    float v = sssq[i] * invn - m * m;
    v = fmaxf(v, 0.0f);
    mu[i]   = m;
    rsig[i] = rsqrtf(v + EPS);
  }
}

// ---- K7: fused BN + ReLU + weighted sum, float4 (agg_max aliases d_out) ----
__global__ void out_kernel(const float* __restrict__ h,
                           const float* __restrict__ h_in,
                           const float* __restrict__ agg_sum,
                           const float* __restrict__ agg_max,
                           const float* __restrict__ deg,
                           const float* __restrict__ mu,
                           const float* __restrict__ rsig,
                           const float* __restrict__ gamma,
                           const float* __restrict__ beta,
                           const float* __restrict__ w,
                           float* __restrict__ out) {
  __shared__ float smu[N_OPS * DIM], srs[N_OPS * DIM], sg[N_OPS * DIM], sb[N_OPS * DIM];
  __shared__ float sw[N_OPS];
  for (int i = threadIdx.x; i < N_OPS * DIM; i += blockDim.x) {
    smu[i] = mu[i]; srs[i] = rsig[i]; sg[i] = gamma[i]; sb[i] = beta[i];
  }
  if (threadIdx.x < N_OPS) sw[threadIdx.x] = w[threadIdx.x];
  __syncthreads();

  const int ngroups = N_NODES * (DIM / 4);
  for (int g = blockIdx.x * blockDim.x + threadIdx.x; g < ngroups;
       g += gridDim.x * blockDim.x) {
    const int n  = g >> 5;
    const int d4 = (g & 31) * 4;
    const size_t off = (size_t)n * DIM + d4;

    const float4 v0 = *reinterpret_cast<const float4*>(h + off);
    const float4 v1 = *reinterpret_cast<const float4*>(h_in + off);
    const float4 v2 = *reinterpret_cast<const float4*>(agg_sum + off);
    const float4 v4 = *reinterpret_cast<const float4*>(agg_max + off);
    const float dg  = deg[n];
    const float inv = 1.0f / fmaxf(dg, 1.0f);

    float vals[N_OPS][4];
    vals[0][0] = v0.x; vals[0][1] = v0.y; vals[0][2] = v0.z; vals[0][3] = v0.w;
    vals[1][0] = v1.x; vals[1][1] = v1.y; vals[1][2] = v1.z; vals[1][3] = v1.w;
    vals[2][0] = v2.x; vals[2][1] = v2.y; vals[2][2] = v2.z; vals[2][3] = v2.w;
    vals[3][0] = v2.x * inv; vals[3][1] = v2.y * inv;
    vals[3][2] = v2.z * inv; vals[3][3] = v2.w * inv;
    vals[4][0] = v4.x; vals[4][1] = v4.y; vals[4][2] = v4.z; vals[4][3] = v4.w;

    float acc[4] = {0.0f, 0.0f, 0.0f, 0.0f};
#pragma unroll
    for (int b = 0; b < N_OPS; ++b) {
      const float wb = sw[b];
#pragma unroll
      for (int c = 0; c < 4; ++c) {
        const int dd = b * DIM + d4 + c;
        const float xh = (vals[b][c] - smu[dd]) * srs[dd];
        const float y  = fmaf(sg[dd], xh, sb[dd]);
        acc[c] = fmaf(wb, fmaxf(y, 0.0f), acc[c]);
      }
    }
    *reinterpret_cast<float4*>(out + off) = make_float4(acc[0], acc[1], acc[2], acc[3]);
  }
}

extern "C" void kernel_launch(void* const* d_in, const int* in_sizes, int n_in,
                              void* d_out, int out_size, void* d_ws, size_t ws_size,
                              hipStream_t stream) {
  const float* w     = (const float*)d_in[0];
  const int*   ei    = (const int*)d_in[1];
  const float* h     = (const float*)d_in[2];
  const float* h_in  = (const float*)d_in[3];
  const float* gamma = (const float*)d_in[4];
  const float* beta  = (const float*)d_in[5];
  float* out = (float*)d_out;

  const size_t ND = (size_t)N_NODES * DIM;
  float* ws       = (float*)d_ws;
  float* agg_sum  = ws;                               // ND floats
  int*   cnt      = (int*)(ws + ND);                  // N ints      <- zeroed
  float* ssum     = (float*)(cnt + N_NODES);          // 640         <- zeroed
  float* sssq     = ssum + N_OPS * DIM;               // 640         <- zeroed
  float* mu       = sssq + N_OPS * DIM;               // 640
  float* rsig     = mu + N_OPS * DIM;                 // 640
  int*   offs     = (int*)(rsig + N_OPS * DIM);       // N+1 ints
  int*   cursor   = offs + N_NODES + 1;               // N ints
  float* deg      = (float*)(cursor + N_NODES);       // N floats
  int*   csr_src  = (int*)(deg + N_NODES);            // E ints
  float* agg_max  = out;                              // ND floats (overwritten last)

  hipMemsetAsync(cnt, 0, (N_NODES + 2 * N_OPS * DIM) * sizeof(int), stream);

  hist_kernel<<<(N_EDGES + 255) / 256, 256, 0, stream>>>(ei, cnt);
  scan_kernel<<<1, 1024, 0, stream>>>(cnt, offs, cursor);
  csr_fill_kernel<<<(N_EDGES + 255) / 256, 256, 0, stream>>>(ei, cursor, csr_src);
  stats_h_kernel<<<512, 256, 0, stream>>>(h, h_in, ssum, sssq);
  gather_kernel<<<1024, 256, 0, stream>>>(csr_src, offs, h, agg_sum, agg_max, deg,
                                          ssum, sssq);
  finalize_stats<<<(N_OPS * DIM + 255) / 256, 256, 0, stream>>>(ssum, sssq, mu, rsig);
  out_kernel<<<2048, 256, 0, stream>>>(h, h_in, agg_sum, agg_max, deg, mu, rsig,
                                       gamma, beta, w, out);
}